// Round 10
// baseline (197.742 us; speedup 1.0000x reference)
//
#include <hip/hip_runtime.h>
#include <hip/hip_bf16.h>
#include <math.h>

// ---------------- constants ----------------
#define HDIM 128
#define SCAN_B 256
#define NBLK 256          // edge blocks for hist/scatter passes
#define BPAD 1800         // per-bucket extra CSR capacity for padding (multiple of 8)

typedef short bfrag __attribute__((ext_vector_type(8)));   // 8 bf16 (4 VGPRs)
typedef float f32x4 __attribute__((ext_vector_type(4)));   // 4 fp32 acc

__device__ inline unsigned short f2bf_rne(float x) {
    unsigned u = __float_as_uint(x);
    u = (u + 0x7fffu + ((u >> 16) & 1u)) >> 16;
    return (unsigned short)u;
}
__device__ inline float bf_lo(unsigned u) { return __uint_as_float(u << 16); }
__device__ inline float bf_hi(unsigned u) { return __uint_as_float(u & 0xffff0000u); }

// ---------------- device bodies ----------------

// Pass A: per-block LDS coarse histogram (dst>>8); no global atomics.
__device__ inline void hist_body(int b, const int* __restrict__ dst,
                                 int* __restrict__ hist, int E, int chunk, int nbuck) {
    __shared__ int hl[256];
    int t = threadIdx.x;
    hl[t] = 0;
    __syncthreads();
    int start = b * chunk, end = min(E, start + chunk);
    for (int e = start + t; e < end; e += 256) atomicAdd(&hl[dst[e] >> 8], 1);
    __syncthreads();
    if (t < nbuck) hist[t * NBLK + b] = hl[t];
}

// W -> fragment-ordered bf16 hi/lo, column-permuted: physical slot (nt, lm)
// carries logical column n_l = lm*8 + nt (so epilogue stores are 16B packed).
__device__ inline void wfrag_body(int b, const float* __restrict__ W1,
                                  const float* __restrict__ W2,
                                  unsigned short* __restrict__ w1h,
                                  unsigned short* __restrict__ w1l,
                                  unsigned short* __restrict__ w2h,
                                  unsigned short* __restrict__ w2l) {
    const float* W = (b < 64) ? W1 : W2;
    unsigned short* whi = (b < 64) ? w1h : w2h;
    unsigned short* wlo = (b < 64) ? w1l : w2l;
    int idx = (b & 63) * 256 + threadIdx.x;     // 0..16383
    int k = idx >> 7;
    int n = idx & 127;
    int kt = k >> 5, q = (k >> 3) & 3, j = k & 7;
    int lm = n >> 3, nt = n & 7;
    int lane = q * 16 + lm;
    int o = ((kt * 8 + nt) * 64 + lane) * 8 + j;
    float x = W[idx];
    unsigned short hb = f2bf_rne(x);
    float hf = __uint_as_float(((unsigned)hb) << 16);
    unsigned short lb = f2bf_rne(x - hf);
    whi[o] = hb;
    wlo[o] = lb;
}

// Pass C: scatter edges into bucket-sorted order via LDS cursors (no global atomics).
__device__ inline void scatter_body(int b, const int* __restrict__ srcv,
                                    const int* __restrict__ dstv,
                                    const int* __restrict__ hscan,
                                    int2* __restrict__ sorted,
                                    int E, int chunk, int nbuck) {
    __shared__ int cur[256];
    int t = threadIdx.x;
    if (t < nbuck) cur[t] = hscan[t * NBLK + b];
    __syncthreads();
    int start = b * chunk, end = min(E, start + chunk);
    for (int e = start + t; e < end; e += 256) {
        int d = dstv[e];
        int pos = atomicAdd(&cur[d >> 8], 1);
        sorted[pos] = make_int2(srcv[e], d);
    }
}

// MFMA GEMM (fp32 A), 64-row tiles, split 3-MFMA: C ~= Ah*Wh + Al*Wh + Ah*Wl
#define GBM 64
__device__ inline void gemm_f32_body(int b, const float* __restrict__ A,
                                     const unsigned short* __restrict__ whi,
                                     const unsigned short* __restrict__ wlo,
                                     unsigned short* __restrict__ C, int Nrows) {
    int tid = threadIdx.x;
    int w = tid >> 6, L = tid & 63;
    int lm = L & 15, lq = L >> 4;
    int row0 = b * GBM + w * 16;

    f32x4 acc[8];
#pragma unroll
    for (int nt = 0; nt < 8; ++nt) acc[nt] = (f32x4)(0.f);

#pragma unroll
    for (int kt = 0; kt < 4; ++kt) {
        int gr = row0 + lm;
        float4 v0 = make_float4(0.f, 0.f, 0.f, 0.f);
        float4 v1 = v0;
        if (gr < Nrows) {
            const float* p = &A[(size_t)gr * HDIM + kt * 32 + lq * 8];
            v0 = *(const float4*)p;
            v1 = *(const float4*)(p + 4);
        }
        float xv[8] = {v0.x, v0.y, v0.z, v0.w, v1.x, v1.y, v1.z, v1.w};
        bfrag ah, al;
#pragma unroll
        for (int j = 0; j < 8; ++j) {
            float x = xv[j];
            unsigned short hb = f2bf_rne(x);
            float hf = __uint_as_float(((unsigned)hb) << 16);
            unsigned short lb = f2bf_rne(x - hf);
            ah[j] = (short)hb;
            al[j] = (short)lb;
        }
#pragma unroll
        for (int nt = 0; nt < 8; ++nt) {
            int o = ((kt * 8 + nt) * 64 + L) * 8;
            bfrag wh = *(const bfrag*)&whi[o];
            bfrag wl = *(const bfrag*)&wlo[o];
            acc[nt] = __builtin_amdgcn_mfma_f32_16x16x32_bf16(ah, wh, acc[nt], 0, 0, 0);
            acc[nt] = __builtin_amdgcn_mfma_f32_16x16x32_bf16(al, wh, acc[nt], 0, 0, 0);
            acc[nt] = __builtin_amdgcn_mfma_f32_16x16x32_bf16(ah, wl, acc[nt], 0, 0, 0);
        }
    }

#pragma unroll
    for (int i = 0; i < 4; ++i) {
        int gr = row0 + lq * 4 + i;
        if (gr < Nrows) {
            bfrag e;
#pragma unroll
            for (int nt = 0; nt < 8; ++nt) e[nt] = (short)f2bf_rne(acc[nt][i]);
            *(bfrag*)&C[(size_t)gr * HDIM + lm * 8] = e;
        }
    }
}

// Pass D body: per-bucket PADDED CSR build (LDS atomics only).
// Each node's row is padded to a multiple of 8 with dummy index N (zero row,
// dinv 0) -> gather loops are tail-free and rowstart is 8-aligned.
__device__ inline void csr_body(int b, const int2* __restrict__ sorted,
                                const int* __restrict__ hscan,
                                int* __restrict__ rowstart,
                                int* __restrict__ rowlen,
                                float* __restrict__ dinv,
                                int* __restrict__ csr,
                                int N, int E, int nbuck) {
    __shared__ int cnt[256];
    __shared__ int s[256];
    __shared__ int cur[256];
    int t = threadIdx.x;
    int start = hscan[b * NBLK];
    int end = (b + 1 < nbuck) ? hscan[(b + 1) * NBLK] : E;
    cnt[t] = 0;
    __syncthreads();
    for (int e = start + t; e < end; e += 256)
        atomicAdd(&cnt[sorted[e].y & 255], 1);
    __syncthreads();
    int v = cnt[t];
    int pc = (v + 7) & ~7;              // padded count (multiple of 8)
    s[t] = pc;
    __syncthreads();
    for (int off = 1; off < 256; off <<= 1) {
        int x = (t >= off) ? s[t - off] : 0;
        __syncthreads();
        s[t] += x;
        __syncthreads();
    }
    int pexcl = s[t] - pc;
    int pbase = ((start + 7) & ~7) + b * BPAD;   // 8-aligned; capacity >= real+1793
    int node = b * 256 + t;
    if (node < N) {
        rowstart[node] = pbase + pexcl;
        rowlen[node] = pc;
        dinv[node] = rsqrtf((float)(v + 1));   // +1 self-loop (real degree)
    }
    cur[t] = pbase + pexcl;
    __syncthreads();
    for (int e = start + t; e < end; e += 256) {
        int2 ed = sorted[e];
        int pos = atomicAdd(&cur[ed.y & 255], 1);
        csr[pos] = ed.x;
    }
    // pad own node's slots with dummy index N (no sync needed: slots are private)
    if (node < N) {
        int base2 = pbase + pexcl;
        for (int j = v; j < pc; ++j) csr[base2 + j] = N;
    }
}

// ---------------- megakernel 1: hist || wfrag ----------------
__global__ __launch_bounds__(256) void mega1_kernel(const int* __restrict__ dst,
                                                    int* __restrict__ hist, int E,
                                                    int chunk, int nbuck,
                                                    const float* __restrict__ W1,
                                                    const float* __restrict__ W2,
                                                    unsigned short* __restrict__ w1h,
                                                    unsigned short* __restrict__ w1l,
                                                    unsigned short* __restrict__ w2h,
                                                    unsigned short* __restrict__ w2l) {
    int b = blockIdx.x;
    if (b < NBLK) hist_body(b, dst, hist, E, chunk, nbuck);
    else wfrag_body(b - NBLK, W1, W2, w1h, w1l, w2h, w2l);
}

// ---------------- scatter kernel (bucket sort pass) ----------------
__global__ __launch_bounds__(256) void scatter_kernel(const int* __restrict__ srcv,
                                                      const int* __restrict__ dstv,
                                                      const int* __restrict__ hscan,
                                                      int2* __restrict__ sorted,
                                                      int E, int chunk, int nbuck) {
    scatter_body(blockIdx.x, srcv, dstv, hscan, sorted, E, chunk, nbuck);
}

// ---------------- megakernel 4: csr-build || gemm_f32(layer1) ----------------
// csr depends only on sorted/hscan; gemm depends only on x/W1 frags -> independent.
__global__ __launch_bounds__(256) void mega4_kernel(const int2* __restrict__ sorted,
                                                    const int* __restrict__ hscan,
                                                    int* __restrict__ rowstart,
                                                    int* __restrict__ rowlen,
                                                    float* __restrict__ dinv,
                                                    int* __restrict__ csr,
                                                    int N, int E, int nbuck,
                                                    const float* __restrict__ A,
                                                    const unsigned short* __restrict__ whi,
                                                    const unsigned short* __restrict__ wlo,
                                                    unsigned short* __restrict__ C) {
    int b = blockIdx.x;
    if (b < nbuck) csr_body(b, sorted, hscan, rowstart, rowlen, dinv, csr, N, E, nbuck);
    else gemm_f32_body(b - nbuck, A, whi, wlo, C, N);
}

// ---------------- scan phase 1: per-block inclusive scan ----------------
__global__ __launch_bounds__(SCAN_B) void scan1_kernel(const int* __restrict__ in,
                                                       int* __restrict__ out,
                                                       int* __restrict__ sums, int n) {
    __shared__ int s[SCAN_B];
    int t = threadIdx.x;
    int idx = blockIdx.x * SCAN_B + t;
    int v = (idx < n) ? in[idx] : 0;
    s[t] = v;
    __syncthreads();
    for (int off = 1; off < SCAN_B; off <<= 1) {
        int x = (t >= off) ? s[t - off] : 0;
        __syncthreads();
        s[t] += x;
        __syncthreads();
    }
    if (idx < n) out[idx] = s[t];
    if (t == SCAN_B - 1) sums[blockIdx.x] = s[t];
}

// ---------------- scan phase 2+3 fused; block 0 also zeroes the dummy row ----------------
__global__ __launch_bounds__(SCAN_B) void scan3_kernel(const int* __restrict__ in,
                                                       int* __restrict__ inout,
                                                       const int* __restrict__ sums,
                                                       int n,
                                                       unsigned short* __restrict__ m,
                                                       unsigned short* __restrict__ m2,
                                                       float* __restrict__ dinv, int N) {
    __shared__ int s[SCAN_B];
    int t = threadIdx.x;
    int b = blockIdx.x;                 // gridDim.x <= 256 required
    s[t] = (t < b) ? sums[t] : 0;
    __syncthreads();
    for (int off = SCAN_B / 2; off > 0; off >>= 1) {
        if (t < off) s[t] += s[t + off];
        __syncthreads();
    }
    int base = s[0];
    int idx = b * SCAN_B + t;
    if (idx < n) inout[idx] = inout[idx] - in[idx] + base;
    // dummy node N: zero row in m and m2, dinv[N]=0  (gather padding adds exact +0)
    if (b == 0) {
        unsigned* mr = (unsigned*)(m + (size_t)N * HDIM);
        unsigned* m2r = (unsigned*)(m2 + (size_t)N * HDIM);
        if (t < 64) mr[t] = 0u;
        else if (t < 128) m2r[t - 64] = 0u;
        else if (t == 128) dinv[N] = 0.f;
    }
}

// ---------------- gather primitives ----------------
// WEIGHTED: acc += dinv[s] * m[s]  (layer-1 rows unscaled)
// !WEIGHTED: acc += m[s]           (layer-2 rows pre-scaled by dinv[src])
template <bool W>
__device__ inline void qacc1(float* acc, uint4 uv, float wt) {
    if (W) {
        acc[0] = fmaf(wt, bf_lo(uv.x), acc[0]);
        acc[1] = fmaf(wt, bf_hi(uv.x), acc[1]);
        acc[2] = fmaf(wt, bf_lo(uv.y), acc[2]);
        acc[3] = fmaf(wt, bf_hi(uv.y), acc[3]);
        acc[4] = fmaf(wt, bf_lo(uv.z), acc[4]);
        acc[5] = fmaf(wt, bf_hi(uv.z), acc[5]);
        acc[6] = fmaf(wt, bf_lo(uv.w), acc[6]);
        acc[7] = fmaf(wt, bf_hi(uv.w), acc[7]);
    } else {
        acc[0] += bf_lo(uv.x); acc[1] += bf_hi(uv.x);
        acc[2] += bf_lo(uv.y); acc[3] += bf_hi(uv.y);
        acc[4] += bf_lo(uv.z); acc[5] += bf_hi(uv.z);
        acc[6] += bf_lo(uv.w); acc[7] += bf_hi(uv.w);
    }
}

// Tail-free, ROW-PIPELINED gather: row lengths are multiples of 8, rowstart
// 8-aligned. Batch k+1's index+row+weight loads are issued BEFORE batch k's
// adds, so the adds' waitcnt leaves the next batch's 8 row loads in flight
// (counted vmcnt within the loop body -> in-flight never drains to 0).
// Accumulation order is identical to the non-pipelined loop (bit-exact).
template <bool W>
__device__ inline void qgather(const uint4* __restrict__ m4,
                               const int* __restrict__ csr,
                               const float* __restrict__ dinv,
                               int p, int pend, int t, float* acc) {
    if (p >= pend) return;
    int4 ia = *(const int4*)&csr[p];
    int4 ib = *(const int4*)&csr[p + 4];
    uint4 u0 = m4[(size_t)ia.x * 16 + t];
    uint4 u1 = m4[(size_t)ia.y * 16 + t];
    uint4 u2 = m4[(size_t)ia.z * 16 + t];
    uint4 u3 = m4[(size_t)ia.w * 16 + t];
    uint4 u4 = m4[(size_t)ib.x * 16 + t];
    uint4 u5 = m4[(size_t)ib.y * 16 + t];
    uint4 u6 = m4[(size_t)ib.z * 16 + t];
    uint4 u7 = m4[(size_t)ib.w * 16 + t];
    float w0 = 0.f, w1 = 0.f, w2 = 0.f, w3 = 0.f;
    float w4 = 0.f, w5 = 0.f, w6 = 0.f, w7 = 0.f;
    if (W) {
        w0 = dinv[ia.x]; w1 = dinv[ia.y]; w2 = dinv[ia.z]; w3 = dinv[ia.w];
        w4 = dinv[ib.x]; w5 = dinv[ib.y]; w6 = dinv[ib.z]; w7 = dinv[ib.w];
    }
    for (p += 8; p < pend; p += 8) {
        // ---- issue batch k+1 (indices, rows, weights) ----
        int4 ja = *(const int4*)&csr[p];
        int4 jb = *(const int4*)&csr[p + 4];
        uint4 v0 = m4[(size_t)ja.x * 16 + t];
        uint4 v1 = m4[(size_t)ja.y * 16 + t];
        uint4 v2 = m4[(size_t)ja.z * 16 + t];
        uint4 v3 = m4[(size_t)ja.w * 16 + t];
        uint4 v4 = m4[(size_t)jb.x * 16 + t];
        uint4 v5 = m4[(size_t)jb.y * 16 + t];
        uint4 v6 = m4[(size_t)jb.z * 16 + t];
        uint4 v7 = m4[(size_t)jb.w * 16 + t];
        float x0 = 0.f, x1 = 0.f, x2 = 0.f, x3 = 0.f;
        float x4 = 0.f, x5 = 0.f, x6 = 0.f, x7 = 0.f;
        if (W) {
            x0 = dinv[ja.x]; x1 = dinv[ja.y]; x2 = dinv[ja.z]; x3 = dinv[ja.w];
            x4 = dinv[jb.x]; x5 = dinv[jb.y]; x6 = dinv[jb.z]; x7 = dinv[jb.w];
        }
        // ---- adds for batch k (waits only on u/w; v/x stay in flight) ----
        qacc1<W>(acc, u0, w0); qacc1<W>(acc, u1, w1);
        qacc1<W>(acc, u2, w2); qacc1<W>(acc, u3, w3);
        qacc1<W>(acc, u4, w4); qacc1<W>(acc, u5, w5);
        qacc1<W>(acc, u6, w6); qacc1<W>(acc, u7, w7);
        u0 = v0; u1 = v1; u2 = v2; u3 = v3;
        u4 = v4; u5 = v5; u6 = v6; u7 = v7;
        w0 = x0; w1 = x1; w2 = x2; w3 = x3;
        w4 = x4; w5 = x5; w6 = x6; w7 = x7;
    }
    // ---- drain last batch ----
    qacc1<W>(acc, u0, w0); qacc1<W>(acc, u1, w1);
    qacc1<W>(acc, u2, w2); qacc1<W>(acc, u3, w3);
    qacc1<W>(acc, u4, w4); qacc1<W>(acc, u5, w5);
    qacc1<W>(acc, u6, w6); qacc1<W>(acc, u7, w7);
}

// In-block degree sort: rank the block's 16 nodes by (padded) row length desc so
// each wave's 4 quarter-nodes have similar trip counts. Stashes starts/lengths.
__device__ inline int degree_perm(const int* __restrict__ rowstart,
                                  const int* __restrict__ rowlen,
                                  int* lens, int* rs, int* perm, int n) {
    if (threadIdx.x < 16) {
        int nn = blockIdx.x * 16 + threadIdx.x;
        rs[threadIdx.x] = (nn < n) ? rowstart[nn] : 0;
        lens[threadIdx.x] = (nn < n) ? rowlen[nn] : -1;
    }
    __syncthreads();
    if (threadIdx.x < 16) {
        int L = lens[threadIdx.x];
        int r = 0;
#pragma unroll
        for (int j = 0; j < 16; ++j) {
            int Lj = lens[j];
            r += (Lj > L || (Lj == L && j < (int)threadIdx.x)) ? 1 : 0;
        }
        perm[r] = threadIdx.x;
    }
    __syncthreads();
    return perm[threadIdx.x >> 4];
}

// ---------------- fused agg(layer1) + gemm(layer2): m2 = dinv*bf16(relu(agg)+b1)@W2 ----------------
__global__ __launch_bounds__(256) void agg_gemm_kernel(
        const uint4* __restrict__ m4,
        const int* __restrict__ rowstart,
        const int* __restrict__ rowlen,
        const int* __restrict__ csr,
        const float* __restrict__ dinv,
        const float* __restrict__ bias,
        const unsigned short* __restrict__ whi,   // W2 frags
        const unsigned short* __restrict__ wlo,
        uint4* __restrict__ out_m, int n) {
    __shared__ unsigned short hbuf[16][HDIM + 8];   // bf16 h tile (+16B pad)
    __shared__ float cbuf[16][HDIM + 4];            // fp32 C tile (+16B pad)
    __shared__ int lens[16];
    __shared__ int rs[16];
    __shared__ int perm[16];
    int t = threadIdx.x & 15;

    int pnl = degree_perm(rowstart, rowlen, lens, rs, perm, n);
    int node = blockIdx.x * 16 + pnl;

    // ---- agg phase (processes node `pnl`, writes hbuf[pnl]) ----
    unsigned short hv[8] = {0, 0, 0, 0, 0, 0, 0, 0};
    if (node < n) {
        float dd = dinv[node];
        float acc[8];
        uint4 u = m4[(size_t)node * 16 + t];
        acc[0] = dd * bf_lo(u.x); acc[1] = dd * bf_hi(u.x);
        acc[2] = dd * bf_lo(u.y); acc[3] = dd * bf_hi(u.y);
        acc[4] = dd * bf_lo(u.z); acc[5] = dd * bf_hi(u.z);
        acc[6] = dd * bf_lo(u.w); acc[7] = dd * bf_hi(u.w);
        int p0 = rs[pnl];
        qgather<true>(m4, csr, dinv, p0, p0 + lens[pnl], t, acc);
        float4 b0 = *(const float4*)&bias[t * 8];
        float4 b1 = *(const float4*)&bias[t * 8 + 4];
        float bb[8] = {b0.x, b0.y, b0.z, b0.w, b1.x, b1.y, b1.z, b1.w};
#pragma unroll
        for (int j = 0; j < 8; ++j)
            hv[j] = f2bf_rne(fmaxf(fmaf(dd, acc[j], bb[j]), 0.f));
    }
    *(uint4*)&hbuf[pnl][t * 8] = *(uint4*)hv;
    __syncthreads();

    // ---- gemm phase: each wave does 2 column tiles, all 4 kt ----
    int w = threadIdx.x >> 6, L = threadIdx.x & 63;
    int lm = L & 15, lq = L >> 4;
    f32x4 acc2[2];
    acc2[0] = (f32x4)(0.f);
    acc2[1] = (f32x4)(0.f);
#pragma unroll
    for (int kt = 0; kt < 4; ++kt) {
        bfrag a = *(const bfrag*)&hbuf[lm][kt * 32 + lq * 8];
#pragma unroll
        for (int q2 = 0; q2 < 2; ++q2) {
            int nt = w * 2 + q2;
            int o = ((kt * 8 + nt) * 64 + L) * 8;
            bfrag wh = *(const bfrag*)&whi[o];
            bfrag wl = *(const bfrag*)&wlo[o];
            acc2[q2] = __builtin_amdgcn_mfma_f32_16x16x32_bf16(a, wh, acc2[q2], 0, 0, 0);
            acc2[q2] = __builtin_amdgcn_mfma_f32_16x16x32_bf16(a, wl, acc2[q2], 0, 0, 0);
        }
    }
    // C/D layout: col(in tile)=lane&15, row=(lane>>4)*4+i; logical col = lm*8+nt
#pragma unroll
    for (int q2 = 0; q2 < 2; ++q2) {
        int nt = w * 2 + q2;
#pragma unroll
        for (int i = 0; i < 4; ++i) cbuf[lq * 4 + i][lm * 8 + nt] = acc2[q2][i];
    }
    __syncthreads();

    // ---- repack + pre-scale by dinv + round + store (original node order) ----
    int nl = threadIdx.x >> 4;
    int node_e = blockIdx.x * 16 + nl;
    if (node_e < n) {
        float dde = dinv[node_e];
        float4 r0 = *(const float4*)&cbuf[nl][t * 8];
        float4 r1 = *(const float4*)&cbuf[nl][t * 8 + 4];
        unsigned short ev[8];
        ev[0] = f2bf_rne(dde * r0.x); ev[1] = f2bf_rne(dde * r0.y);
        ev[2] = f2bf_rne(dde * r0.z); ev[3] = f2bf_rne(dde * r0.w);
        ev[4] = f2bf_rne(dde * r1.x); ev[5] = f2bf_rne(dde * r1.y);
        ev[6] = f2bf_rne(dde * r1.z); ev[7] = f2bf_rne(dde * r1.w);
        out_m[(size_t)node_e * 16 + t] = *(uint4*)ev;
    }
}

// ---------------- agg layer 2 fused with global max pool ----------------
// m2 rows pre-scaled by dinv[src] -> pure-add gather; degree-sorted waves.
__global__ __launch_bounds__(256) void agg_pool_kernel(const uint4* __restrict__ m4,
                                                       const int* __restrict__ rowstart,
                                                       const int* __restrict__ rowlen,
                                                       const int* __restrict__ csr,
                                                       const float* __restrict__ dinv,
                                                       const float* __restrict__ bias,
                                                       const int* __restrict__ batch,
                                                       unsigned int* __restrict__ g, int n) {
    __shared__ float smx[16][HDIM];
    __shared__ int sgid[16];
    __shared__ int lens[16];
    __shared__ int rs[16];
    __shared__ int perm[16];
    int t = threadIdx.x & 15;

    int pnl = degree_perm(rowstart, rowlen, lens, rs, perm, n);
    int node = blockIdx.x * 16 + pnl;
    bool valid = node < n;
    if (valid) {
        float dd = dinv[node];
        float acc[8];
        uint4 u = m4[(size_t)node * 16 + t];
        acc[0] = bf_lo(u.x); acc[1] = bf_hi(u.x);
        acc[2] = bf_lo(u.y); acc[3] = bf_hi(u.y);
        acc[4] = bf_lo(u.z); acc[5] = bf_hi(u.z);
        acc[6] = bf_lo(u.w); acc[7] = bf_hi(u.w);
        int p0 = rs[pnl];
        qgather<false>(m4, csr, dinv, p0, p0 + lens[pnl], t, acc);
        float4 b0 = *(const float4*)&bias[t * 8];
        float4 b1 = *(const float4*)&bias[t * 8 + 4];
        float4 r0, r1;
        r0.x = fmaxf(fmaf(dd, acc[0], b0.x), 0.f);
        r0.y = fmaxf(fmaf(dd, acc[1], b0.y), 0.f);
        r0.z = fmaxf(fmaf(dd, acc[2], b0.z), 0.f);
        r0.w = fmaxf(fmaf(dd, acc[3], b0.w), 0.f);
        r1.x = fmaxf(fmaf(dd, acc[4], b1.x), 0.f);
        r1.y = fmaxf(fmaf(dd, acc[5], b1.y), 0.f);
        r1.z = fmaxf(fmaf(dd, acc[6], b1.z), 0.f);
        r1.w = fmaxf(fmaf(dd, acc[7], b1.w), 0.f);
        *(float4*)&smx[pnl][t * 8] = r0;
        *(float4*)&smx[pnl][t * 8 + 4] = r1;
    }
    if (t == 0) sgid[pnl] = valid ? batch[node] : -1;
    __syncthreads();
    // smx/sgid indexed by original node order -> batch runs stay contiguous.
    if (threadIdx.x < HDIM) {
        int c = threadIdx.x;
        int curg = -1;
        float run = 0.f;
#pragma unroll
        for (int r = 0; r < 16; ++r) {
            int gg = sgid[r];
            if (gg < 0) continue;
            if (gg != curg) {
                if (curg >= 0) atomicMax(&g[curg * HDIM + c], __float_as_uint(run));
                curg = gg;
                run = smx[r][c];
            } else {
                run = fmaxf(run, smx[r][c]);
            }
        }
        if (curg >= 0) atomicMax(&g[curg * HDIM + c], __float_as_uint(run));
    }
}

// ---------------- MLP head + log_softmax ----------------
__global__ __launch_bounds__(128) void mlp_kernel(const unsigned int* __restrict__ gbits,
                                                  const float* __restrict__ W3,
                                                  const float* __restrict__ b3,
                                                  const float* __restrict__ W4,
                                                  const float* __restrict__ b4,
                                                  float* __restrict__ out) {
    __shared__ float gs[HDIM];
    __shared__ float r0[HDIM];
    __shared__ float r1[HDIM];
    int j = threadIdx.x;
    int b = blockIdx.x;
    gs[j] = __uint_as_float(gbits[b * HDIM + j]);
    __syncthreads();
    float acc = b3[j];
#pragma unroll 8
    for (int k = 0; k < HDIM; ++k) acc = fmaf(gs[k], W3[k * HDIM + j], acc);
    float z = fmaxf(acc, 0.f);
    r0[j] = z * W4[j * 2 + 0];
    r1[j] = z * W4[j * 2 + 1];
    __syncthreads();
    for (int off = 64; off > 0; off >>= 1) {
        if (j < off) {
            r0[j] += r0[j + off];
            r1[j] += r1[j + off];
        }
        __syncthreads();
    }
    if (j == 0) {
        float l0 = r0[0] + b4[0];
        float l1 = r1[0] + b4[1];
        float mx = fmaxf(l0, l1);
        float lse = mx + logf(expf(l0 - mx) + expf(l1 - mx));
        out[b * 2 + 0] = l0 - lse;
        out[b * 2 + 1] = l1 - lse;
    }
}

extern "C" void kernel_launch(void* const* d_in, const int* in_sizes, int n_in,
                              void* d_out, int out_size, void* d_ws, size_t ws_size,
                              hipStream_t stream) {
    const float* x  = (const float*)d_in[0];
    const float* W1 = (const float*)d_in[1];
    const float* b1 = (const float*)d_in[2];
    const float* W2 = (const float*)d_in[3];
    const float* b2 = (const float*)d_in[4];
    const float* W3 = (const float*)d_in[5];
    const float* b3 = (const float*)d_in[6];
    const float* W4 = (const float*)d_in[7];
    const float* b4 = (const float*)d_in[8];
    const int* ei    = (const int*)d_in[9];
    const int* batch = (const int*)d_in[10];

    const int N = in_sizes[0] / HDIM;   // 50000
    const int E = in_sizes[9] / 2;      // 640000
    const int G = out_size / 2;         // 64
    const int* src = ei;
    const int* dst = ei + E;

    const int nbuck = (N + 255) >> 8;        // 196 (must be <= 256)
    const int nscan = nbuck * NBLK;          // 50176
    const int chunk = (E + NBLK - 1) / NBLK; // 2500

    // ---- workspace layout (16B-aligned blocks) ----
    const int Nr = ((N + 63) / 64) * 64;
    char* wsb = (char*)d_ws;
    size_t o = 0;
    unsigned int* g = (unsigned int*)(wsb + o); o += (size_t)G * HDIM * 4;
    size_t zero_bytes = o;                 // only g needs zeroing
    int* hist = (int*)(wsb + o);           o += (size_t)nscan * 4;
    int* hscan = (int*)(wsb + o);          o += (size_t)nscan * 4;
    int* sums = (int*)(wsb + o);           o += 256 * 4;
    int* rowstart = (int*)(wsb + o);       o += (size_t)(Nr + 64) * 4;
    int* rowlen = (int*)(wsb + o);         o += (size_t)(Nr + 64) * 4;
    float* dinv = (float*)(wsb + o);       o += (size_t)Nr * 4;
    int2* sorted = (int2*)(wsb + o);       o += (size_t)E * 8;
    int* csr = (int*)(wsb + o);            o += ((size_t)E + (size_t)nbuck * BPAD + 2048) * 4;
    unsigned short* wf1h = (unsigned short*)(wsb + o); o += (size_t)HDIM * HDIM * 2;
    unsigned short* wf1l = (unsigned short*)(wsb + o); o += (size_t)HDIM * HDIM * 2;
    unsigned short* wf2h = (unsigned short*)(wsb + o); o += (size_t)HDIM * HDIM * 2;
    unsigned short* wf2l = (unsigned short*)(wsb + o); o += (size_t)HDIM * HDIM * 2;
    unsigned short* m = (unsigned short*)(wsb + o);    o += (size_t)(Nr + 64) * HDIM * 2;
    unsigned short* m2 = (unsigned short*)(wsb + o);   o += (size_t)(Nr + 64) * HDIM * 2;
    (void)ws_size; (void)n_in;

    (void)hipMemsetAsync(d_ws, 0, zero_bytes, stream);

    int sblocks = (nscan + SCAN_B - 1) / SCAN_B;   // 196 (<= 256 required)
    int gemm_blocks = (N + GBM - 1) / GBM;         // 782
    int agg_blocks = (N + 15) / 16;                // 3125

    // K1: hist || wfrag  (independent)
    mega1_kernel<<<NBLK + 128, 256, 0, stream>>>(dst, hist, E, chunk, nbuck,
                                                 W1, W2, wf1h, wf1l, wf2h, wf2l);
    // K2: scan of hist matrix (bucket-major) -> hscan exclusive (2 dispatches);
    //     scan3 block 0 also zeroes dummy row N of m/m2 and dinv[N]
    scan1_kernel<<<sblocks, SCAN_B, 0, stream>>>(hist, hscan, sums, nscan);
    scan3_kernel<<<sblocks, SCAN_B, 0, stream>>>(hist, hscan, sums, nscan, m, m2, dinv, N);
    // K3: scatter (bucket sort) alone -- its output gates csr-build
    scatter_kernel<<<NBLK, 256, 0, stream>>>(src, dst, hscan, sorted, E, chunk, nbuck);
    // K4: csr-build || gemm layer 1  (independent of each other)
    mega4_kernel<<<nbuck + gemm_blocks, 256, 0, stream>>>(sorted, hscan, rowstart,
                                                          rowlen, dinv, csr,
                                                          N, E, nbuck,
                                                          x, wf1h, wf1l, m);
    // K5: fused agg(layer1) + gemm(layer2) -> m2 (dinv-pre-scaled)
    agg_gemm_kernel<<<agg_blocks, 256, 0, stream>>>((const uint4*)m, rowstart, rowlen,
                                                    csr, dinv, b1, wf2h, wf2l,
                                                    (uint4*)m2, N);
    // K6: agg layer 2 + global max pool
    agg_pool_kernel<<<agg_blocks, 256, 0, stream>>>((const uint4*)m2, rowstart, rowlen,
                                                    csr, dinv, b2, batch, g, N);
    // K7: MLP head + log_softmax
    mlp_kernel<<<G, 128, 0, stream>>>(g, W3, b3, W4, b4, (float*)d_out);
}